// Round 1
// baseline (32915.259 us; speedup 1.0000x reference)
//
#include <hip/hip_runtime.h>
#include <hip/hip_cooperative_groups.h>
#include <cmath>

namespace cg = cooperative_groups;

constexpr int NB  = 64;      // batch
constexpr int NT  = 512;     // time
constexpr int ND  = 256;     // input dim
constexpr int NH  = 1024;    // hidden
constexpr int ON  = 50257;   // vocab

// ---------------------------------------------------------------------------
// GRU recurrence: cooperative kernel, one grid.sync per timestep.
// grid = 256 blocks x 256 threads. Block owns 4 hidden units (1 per wave).
// Thread (wave q, lane b) computes gates for unit j = blockIdx*4+q, batch b.
// h layout in ws: [NH][NB] f32 (so lane-b reads/writes are coalesced).
// LDS: 128 KiB -> forces 1 block/CU so 256 blocks are co-resident.
// ---------------------------------------------------------------------------
__global__ __launch_bounds__(256, 1)
void gru_rec_kernel(const float* __restrict__ x,     // [NB,NT,ND]
                    const float* __restrict__ Wih,   // [3*NH, ND]
                    const float* __restrict__ Whh,   // [3*NH, NH]
                    const float* __restrict__ bih,   // [3*NH]
                    const float* __restrict__ bhh,   // [3*NH]
                    float* __restrict__ hbuf0,       // [NH][NB]
                    float* __restrict__ hbuf1)       // [NH][NB]
{
    cg::grid_group grid = cg::this_grid();
    extern __shared__ float lds[];                   // 32768 floats = 128 KiB

    const int tid = threadIdx.x;
    const int b   = tid & 63;
    const int q   = __builtin_amdgcn_readfirstlane(tid >> 6);  // wave id 0..3
    const int j   = blockIdx.x * 4 + q;                        // hidden unit

    const float* __restrict__ wRh = Whh + (size_t)(0*NH + j) * NH;
    const float* __restrict__ wZh = Whh + (size_t)(1*NH + j) * NH;
    const float* __restrict__ wNh = Whh + (size_t)(2*NH + j) * NH;
    const float* __restrict__ wRi = Wih + (size_t)(0*NH + j) * ND;
    const float* __restrict__ wZi = Wih + (size_t)(1*NH + j) * ND;
    const float* __restrict__ wNi = Wih + (size_t)(2*NH + j) * ND;

    const float bR  = bih[0*NH + j] + bhh[0*NH + j];
    const float bZ  = bih[1*NH + j] + bhh[1*NH + j];
    const float bNi = bih[2*NH + j];
    const float bNh = bhh[2*NH + j];

    for (int t = 0; t < NT; ++t) {
        const float* __restrict__ hin  = (t & 1) ? hbuf1 : hbuf0;
        float*       __restrict__ hout = (t & 1) ? hbuf0 : hbuf1;

        grid.sync();   // all writes of step t-1 visible

        float aR = bR, aZ = bZ, aNi = bNi, aNh = bNh;

        // ---- recurrent part: h . W_hh rows, two 512-k chunks through LDS ----
        for (int c = 0; c < 2; ++c) {
            __syncthreads();
            {
                const float4* __restrict__ src = (const float4*)(hin + c * (512*64));
                float4* dst = (float4*)lds;
                #pragma unroll 4
                for (int i = 0; i < 32; ++i)
                    dst[tid + i*256] = src[tid + i*256];
            }
            __syncthreads();
            const float* __restrict__ wR = wRh + c*512;
            const float* __restrict__ wZ = wZh + c*512;
            const float* __restrict__ wN = wNh + c*512;
            #pragma unroll 8
            for (int k = 0; k < 512; ++k) {
                const float hv = lds[k*64 + b];          // lane=b: conflict-free
                aR  = fmaf(hv, wR[k], aR);
                aZ  = fmaf(hv, wZ[k], aZ);
                aNh = fmaf(hv, wN[k], aNh);
            }
        }

        // ---- input part: stage x_t transposed into LDS (xor-swizzled) ------
        __syncthreads();
        #pragma unroll 4
        for (int i = 0; i < 16; ++i) {
            const int idx = tid + i*256;
            const int bb  = idx >> 6;      // wave-uniform batch row
            const int dg  = idx & 63;      // per-lane float4 index along D
            const float4 v = ((const float4*)(x + ((size_t)bb*NT + t) * ND))[dg];
            const int d0 = dg * 4;
            // swizzle g(d) = (d>>2) ^ ((d&3)<<4); d = 4*dg + m  ->  g = dg ^ (m<<4)
            lds[(d0+0)*64 + (bb ^  dg       )] = v.x;
            lds[(d0+1)*64 + (bb ^ (dg ^ 16) )] = v.y;
            lds[(d0+2)*64 + (bb ^ (dg ^ 32) )] = v.z;
            lds[(d0+3)*64 + (bb ^ (dg ^ 48) )] = v.w;
        }
        __syncthreads();
        #pragma unroll 8
        for (int k = 0; k < ND; ++k) {
            const int gk = (k >> 2) ^ ((k & 3) << 4);
            const float xv = lds[k*64 + (b ^ gk)];
            aR  = fmaf(xv, wRi[k], aR);
            aZ  = fmaf(xv, wZi[k], aZ);
            aNi = fmaf(xv, wNi[k], aNi);
        }

        // ---- gates ---------------------------------------------------------
        const float r = 1.0f / (1.0f + expf(-aR));
        const float z = 1.0f / (1.0f + expf(-aZ));
        const float n = tanhf(aNi + r * aNh);
        const float hprev = hin[j*64 + b];
        hout[j*64 + b] = (1.0f - z) * n + z * hprev;
    }
}

// ---------------------------------------------------------------------------
// Final dense: logits[b][o] = sum_k h[b][k]*Wd[o][k] + bd[o]
// Block computes 64 outputs x 64 batch; K chunked by 128 through LDS.
// W tile stored transposed [k][o] with stride 68 -> conflict-free b128 reads.
// ---------------------------------------------------------------------------
constexpr int KC = 128;

__global__ __launch_bounds__(256, 1)
void dense_kernel(const float* __restrict__ hfin,   // [NH][NB]
                  const float* __restrict__ Wd,     // [ON, NH]
                  const float* __restrict__ bd,     // [ON]
                  float* __restrict__ out)          // [NB][ON]
{
    extern __shared__ float lds[];
    float* hs  = lds;              // [KC][64]
    float* wsm = lds + KC*64;      // [KC][68]

    const int tid = threadIdx.x;
    const int o0  = blockIdx.x * 64;
    const int ot  = tid & 15;
    const int tb  = tid >> 4;      // 0..15
    const int b0  = tb * 4;
    const int ol  = ot * 4;

    float acc[4][4];
    #pragma unroll
    for (int i = 0; i < 4; ++i)
        #pragma unroll
        for (int jb = 0; jb < 4; ++jb) acc[i][jb] = 0.0f;

    for (int c = 0; c < NH/KC; ++c) {
        __syncthreads();
        {   // stage h chunk: KC*64 floats, linear float4 copy
            const float4* src = (const float4*)(hfin + c*KC*64);
            float4* dst = (float4*)hs;
            #pragma unroll
            for (int i = 0; i < (KC*16)/256; ++i)          // 8
                dst[tid + i*256] = src[tid + i*256];
        }
        {   // stage W tile transposed: rows o0..o0+63, cols c*KC..+KC-1
            #pragma unroll
            for (int ii = 0; ii < (64*(KC/4))/256; ++ii) { // 8
                const int i  = tid + ii*256;
                const int r_ = i >> 5;                     // row (KC/4=32 f4/row)
                const int f4 = i & 31;
                const int o  = o0 + r_;
                float4 v = make_float4(0.f, 0.f, 0.f, 0.f);
                if (o < ON)
                    v = ((const float4*)(Wd + (size_t)o*NH + c*KC))[f4];
                const int k0 = f4*4;
                wsm[(k0+0)*68 + r_] = v.x;
                wsm[(k0+1)*68 + r_] = v.y;
                wsm[(k0+2)*68 + r_] = v.z;
                wsm[(k0+3)*68 + r_] = v.w;
            }
        }
        __syncthreads();
        #pragma unroll 4
        for (int k = 0; k < KC; ++k) {
            const float4 hv = *(const float4*)&hs[k*64 + b0];
            const float4 wv = *(const float4*)&wsm[k*68 + ol];
            acc[0][0] = fmaf(wv.x, hv.x, acc[0][0]);
            acc[0][1] = fmaf(wv.x, hv.y, acc[0][1]);
            acc[0][2] = fmaf(wv.x, hv.z, acc[0][2]);
            acc[0][3] = fmaf(wv.x, hv.w, acc[0][3]);
            acc[1][0] = fmaf(wv.y, hv.x, acc[1][0]);
            acc[1][1] = fmaf(wv.y, hv.y, acc[1][1]);
            acc[1][2] = fmaf(wv.y, hv.z, acc[1][2]);
            acc[1][3] = fmaf(wv.y, hv.w, acc[1][3]);
            acc[2][0] = fmaf(wv.z, hv.x, acc[2][0]);
            acc[2][1] = fmaf(wv.z, hv.y, acc[2][1]);
            acc[2][2] = fmaf(wv.z, hv.z, acc[2][2]);
            acc[2][3] = fmaf(wv.z, hv.w, acc[2][3]);
            acc[3][0] = fmaf(wv.w, hv.x, acc[3][0]);
            acc[3][1] = fmaf(wv.w, hv.y, acc[3][1]);
            acc[3][2] = fmaf(wv.w, hv.z, acc[3][2]);
            acc[3][3] = fmaf(wv.w, hv.w, acc[3][3]);
        }
    }

    #pragma unroll
    for (int i = 0; i < 4; ++i) {
        const int o = o0 + ol + i;
        if (o < ON) {
            const float bias = bd[o];
            #pragma unroll
            for (int jb = 0; jb < 4; ++jb)
                out[(size_t)(b0 + jb) * ON + o] = acc[i][jb] + bias;
        }
    }
}

// ---------------------------------------------------------------------------
// Row-wise log_softmax over out[b][0..ON), in place. One block per row.
// ---------------------------------------------------------------------------
__global__ __launch_bounds__(1024, 1)
void logsoftmax_kernel(float* __restrict__ out)
{
    __shared__ float red[1024];
    const int bidx = blockIdx.x;
    float* __restrict__ row = out + (size_t)bidx * ON;
    const int tid = threadIdx.x;

    float m = -1e30f;
    for (int i = tid; i < ON; i += 1024) m = fmaxf(m, row[i]);
    red[tid] = m;
    __syncthreads();
    for (int s = 512; s > 0; s >>= 1) {
        if (tid < s) red[tid] = fmaxf(red[tid], red[tid + s]);
        __syncthreads();
    }
    const float M = red[0];
    __syncthreads();

    float ssum = 0.0f;
    for (int i = tid; i < ON; i += 1024) ssum += expf(row[i] - M);
    red[tid] = ssum;
    __syncthreads();
    for (int s = 512; s > 0; s >>= 1) {
        if (tid < s) red[tid] += red[tid + s];
        __syncthreads();
    }
    const float lse = M + logf(red[0]);

    for (int i = tid; i < ON; i += 1024) row[i] -= lse;
}

// ---------------------------------------------------------------------------
extern "C" void kernel_launch(void* const* d_in, const int* in_sizes, int n_in,
                              void* d_out, int out_size, void* d_ws, size_t ws_size,
                              hipStream_t stream)
{
    const float* x   = (const float*)d_in[0];   // in_seq  [64,512,256]
    const float* Wih = (const float*)d_in[1];   // [3072,256]
    const float* Whh = (const float*)d_in[2];   // [3072,1024]
    const float* bih = (const float*)d_in[3];   // [3072]
    const float* bhh = (const float*)d_in[4];   // [3072]
    const float* Wd  = (const float*)d_in[5];   // [50257,1024]
    const float* bd  = (const float*)d_in[6];   // [50257]
    float* out = (float*)d_out;                 // [64,50257] f32

    float* h0 = (float*)d_ws;                   // [NH][NB] ping
    float* h1 = h0 + NH*NB;                     // [NH][NB] pong

    // h(0) = 0 (ws is poisoned 0xAA before every timed launch)
    hipMemsetAsync(d_ws, 0, (size_t)2 * NH * NB * sizeof(float), stream);

    void* args[7];
    args[0] = (void*)&x;   args[1] = (void*)&Wih; args[2] = (void*)&Whh;
    args[3] = (void*)&bih; args[4] = (void*)&bhh; args[5] = (void*)&h0;
    args[6] = (void*)&h1;
    hipLaunchCooperativeKernel(reinterpret_cast<void*>(gru_rec_kernel),
                               dim3(256), dim3(256), args, 131072u, stream);

    dense_kernel<<<(ON + 63)/64, 256, (KC*64 + KC*68)*sizeof(float), stream>>>(
        h0, Wd, bd, out);
    logsoftmax_kernel<<<NB, 1024, 0, stream>>>(out);
}